// Round 7
// baseline (54.577 us; speedup 1.0000x reference)
//
#include <hip/hip_runtime.h>

// Problem constants (reference: B=1, T=2048, H=32, D=64, SCALE=1/64, DEG=2)
#define T_DIM 2048
#define H_DIM 32
#define D_DIM 64
#define SCALE_F 0.015625f
#define TILE_STRIDE 2048    // ushorts per (h, 32-row frag tile) = 4KB

typedef unsigned short ushort;
typedef __attribute__((ext_vector_type(8))) short short8;   // 8 bf16
typedef __attribute__((ext_vector_type(16))) float f32x16;  // 32x32 MFMA acc
typedef __attribute__((ext_vector_type(2))) float f32x2;    // packed f32 math

#define MFMA32(A, B, C) __builtin_amdgcn_mfma_f32_32x32x16_bf16((A), (B), (C), 0, 0, 0)

// ---------------------------------------------------------------------------
// Kernel 1: per-head inclusive cumsum of g over T -> gc stored [H][T]  (B=1)
// ---------------------------------------------------------------------------
__global__ __launch_bounds__(256)
void cumsum_g_kernel(const float* __restrict__ g, float* __restrict__ gc) {
    const int h = blockIdx.x;
    const int tid = threadIdx.x;
    const int PER = T_DIM / 256;        // 8

    __shared__ float sums[256];

    float loc[8];
    float run = 0.f;
    const int t0 = tid * PER;
    for (int i = 0; i < PER; ++i) {
        run += g[(size_t)(t0 + i) * H_DIM + h];
        loc[i] = run;
    }
    sums[tid] = run;
    __syncthreads();

    for (int off = 1; off < 256; off <<= 1) {
        float vv = (tid >= off) ? sums[tid - off] : 0.f;
        __syncthreads();
        sums[tid] += vv;
        __syncthreads();
    }
    float excl = (tid == 0) ? 0.f : sums[tid - 1];

    for (int i = 0; i < PER; ++i)
        gc[(size_t)h * T_DIM + t0 + i] = excl + loc[i];
}

// ---------------------------------------------------------------------------
__device__ __forceinline__ ushort f2bf(float x) {
    unsigned u = __float_as_uint(x);
    unsigned r = (u + 0x7fffu + ((u >> 16) & 1u)) >> 16;
    return (ushort)r;
}

// ---------------------------------------------------------------------------
// Prep: frag-major bf16 buffers so ALL main-loop frag loads coalesce.
//   qfrag/kfrag: [h][t32][ks(4)][hi(2)][l31(32)][8]  content q̂/k̂[32*t32+l31][16ks+8hi+j]
//   vfrag:       [h][s32][dblk(2)][kh2(2)][hi(2)][l31(32)][8]
//                 content v̂[32*s32+16kh2+8hi+j][32dblk+l31]
// q̂ = q*SCALE*exp(gc/2), k̂ = k*exp(-gc/2), v̂ = bf16(v).
// ---------------------------------------------------------------------------
__global__ __launch_bounds__(256)
void prep_kernel(const float* __restrict__ q, const float* __restrict__ k,
                 const float* __restrict__ v, const float* __restrict__ gc,
                 ushort* __restrict__ qfrag, ushort* __restrict__ kfrag,
                 ushort* __restrict__ vfrag) {
    __shared__ ushort qt_l[64 * 64];   // swizzled [row][slot] 16B chunks
    __shared__ ushort kt_l[64 * 64];

    const int h   = blockIdx.x;
    const int tt  = blockIdx.y;        // 64-row chunk
    const int tid = threadIdx.x;

    // ---- stage q̂,k̂ rows into swizzled LDS (coalesced f32 reads) ----
    {
        const int r    = tid >> 2;          // 0..63
        const int dseg = (tid & 3) * 16;    // 16 floats
        const int t    = tt * 64 + r;
        const float gct = gc[(size_t)h * T_DIM + t];
        const float eq = SCALE_F * __expf(0.5f * gct);
        const float ek = __expf(-0.5f * gct);
        const float* qp = q + ((size_t)t * H_DIM + h) * 64 + dseg;
        const float* kp = k + ((size_t)t * H_DIM + h) * 64 + dseg;
        union { ushort u[16]; uint4 uu[2]; } oq, ok;
#pragma unroll
        for (int i = 0; i < 16; ++i) {
            oq.u[i] = f2bf(qp[i] * eq);
            ok.u[i] = f2bf(kp[i] * ek);
        }
        const int c0 = (tid & 3) * 2;       // 16B chunk index base
#pragma unroll
        for (int cc = 0; cc < 2; ++cc) {
            const int slot = (c0 + cc) ^ (r & 7);
            *reinterpret_cast<uint4*>(&qt_l[r * 64 + slot * 8]) = oq.uu[cc];
            *reinterpret_cast<uint4*>(&kt_l[r * 64 + slot * 8]) = ok.uu[cc];
        }
    }
    __syncthreads();

    // ---- q/k frag writes: 512 16B-chunks each, coalesced stores ----
#pragma unroll
    for (int n = 0; n < 2; ++n) {
        const int ch   = tid + 256 * n;     // 0..511
        const int l31  = ch & 31;
        const int hi   = (ch >> 5) & 1;
        const int ks   = (ch >> 6) & 3;
        const int t32r = ch >> 8;           // 0/1
        const int row  = t32r * 32 + l31;
        const int slot = (2 * ks + hi) ^ (row & 7);
        uint4 qq = *reinterpret_cast<const uint4*>(&qt_l[row * 64 + slot * 8]);
        uint4 kk = *reinterpret_cast<const uint4*>(&kt_l[row * 64 + slot * 8]);
        const size_t base = ((size_t)h * 64 + tt * 2 + t32r) * TILE_STRIDE
                          + (size_t)(((ks * 2 + hi) * 32) + l31) * 8;
        *reinterpret_cast<uint4*>(qfrag + base) = qq;
        *reinterpret_cast<uint4*>(kfrag + base) = kk;
    }

    // ---- v frags: direct global gather (all loads/stores coalesced) ----
#pragma unroll
    for (int n = 0; n < 2; ++n) {
        const int c9   = (tid >> 5) + 8 * n;  // 0..15
        const int l31  = tid & 31;
        const int hi   = c9 & 1;
        const int kh2  = (c9 >> 1) & 1;
        const int dblk = (c9 >> 2) & 1;
        const int s32r = c9 >> 3;
        const int tb = tt * 64 + s32r * 32 + kh2 * 16 + hi * 8;
        union { ushort u[8]; uint4 uu; } ov;
#pragma unroll
        for (int j = 0; j < 8; ++j)
            ov.u[j] = f2bf(v[((size_t)(tb + j) * H_DIM + h) * 64 + dblk * 32 + l31]);
        const size_t base = ((size_t)h * 64 + tt * 2 + s32r) * TILE_STRIDE
                          + (size_t)((((dblk * 2 + kh2) * 2 + hi) * 32) + l31) * 8;
        *reinterpret_cast<uint4*>(vfrag + base) = ov.uu;
    }
}

// ---------------------------------------------------------------------------
// Main kernel helpers
// ---------------------------------------------------------------------------
__device__ __forceinline__ short8 ld8(const ushort* p) {
    return *reinterpret_cast<const short8*>(p);
}

__device__ __forceinline__ unsigned cvt_pk_bf16(float lo, float hi) {
    unsigned r;
    asm("v_cvt_pk_bf16_f32 %0, %1, %2" : "=v"(r) : "v"(lo), "v"(hi));
    return r;
}

// Pack 8 f32 W-values (4 f32x2 pairs, C-layout half) into the PV A-operand
// fragment via cvt_pk + permlane32_swap. (Layout verified R3-R6.)
__device__ __forceinline__ short8 pack_w2(const f32x2* w2) {
    unsigned p0 = cvt_pk_bf16(w2[0][0], w2[0][1]);
    unsigned p1 = cvt_pk_bf16(w2[1][0], w2[1][1]);
    unsigned p2 = cvt_pk_bf16(w2[2][0], w2[2][1]);
    unsigned p3 = cvt_pk_bf16(w2[3][0], w2[3][1]);
    asm("v_permlane32_swap_b32 %0, %1" : "+v"(p0), "+v"(p2));
    asm("v_permlane32_swap_b32 %0, %1" : "+v"(p1), "+v"(p3));
    union { unsigned u[4]; short8 s; } af;
    af.u[0] = p0; af.u[1] = p1; af.u[2] = p2; af.u[3] = p3;
    return af.s;
}

// Async 16B-per-lane global -> LDS copy (wave-uniform LDS base + lane*16).
__device__ __forceinline__ void gll16(const void* g, void* l) {
    __builtin_amdgcn_global_load_lds(
        (const __attribute__((address_space(1))) unsigned int*)g,
        (__attribute__((address_space(3))) unsigned int*)l, 16, 0, 0);
}

// Stage one 64-s period (K 8KB + V 8KB) into a 16KB LDS buffer, linearly.
__device__ __forceinline__ void stage16k(ushort* ldst, const char* ksrc,
                                         const char* vsrc, int tid) {
    char* lb = (char*)ldst + (tid >> 6) * 1024;  // wave-uniform base
    const int lo = tid * 16;                     // lane-linear global offset
    gll16(ksrc + lo,        lb);
    gll16(ksrc + 4096 + lo, lb + 4096);
    gll16(vsrc + lo,        lb + 8192);
    gll16(vsrc + 4096 + lo, lb + 12288);
}

// One 32s x 32q unit from LDS. MODE 0: full, 1: diagonal (s_local <= l31).
// ldsK: one K frag tile (2048 ushorts); ldsV: one V frag tile.
template<int MODE>
__device__ __forceinline__ void unit32(
    const ushort* ldsK, const ushort* ldsV,
    int lofs, int hi, int l31,
    const short8 (&qr)[4], f32x16& o0, f32x16& o1, f32x2& den2)
{
    const short8 kf0 = ld8(ldsK + lofs);
    const short8 kf1 = ld8(ldsK + 512 + lofs);
    const short8 kf2 = ld8(ldsK + 1024 + lofs);
    const short8 kf3 = ld8(ldsK + 1536 + lofs);
    const short8 vf0 = ld8(ldsV + lofs);           // dblk0 kh2=0
    const short8 vf1 = ld8(ldsV + 512 + lofs);     // dblk0 kh2=1
    const short8 vf2 = ld8(ldsV + 1024 + lofs);    // dblk1 kh2=0
    const short8 vf3 = ld8(ldsV + 1536 + lofs);    // dblk1 kh2=1

    f32x16 c;
#pragma unroll
    for (int i = 0; i < 16; ++i) c[i] = 0.f;
    c = MFMA32(kf0, qr[0], c);
    c = MFMA32(kf1, qr[1], c);
    c = MFMA32(kf2, qr[2], c);
    c = MFMA32(kf3, qr[3], c);

    f32x2 w2[8];
#pragma unroll
    for (int i = 0; i < 8; ++i) {
        const int r0 = 2 * i;
        f32x2 x; x[0] = c[r0]; x[1] = c[r0 + 1];
        f32x2 ww = x * x;
        if (MODE == 1) {
            const int sl0 = (r0 & 3) + 8 * (r0 >> 2) + 4 * hi;
            ww[0] = (sl0 <= l31) ? ww[0] : 0.f;
            ww[1] = (sl0 + 1 <= l31) ? ww[1] : 0.f;
        }
        w2[i] = ww;
        den2 += ww;
    }
    const short8 a0 = pack_w2(&w2[0]);     // kh2 = 0
    o0 = MFMA32(a0, vf0, o0);
    o1 = MFMA32(a0, vf2, o1);
    const short8 a1 = pack_w2(&w2[4]);     // kh2 = 1
    o0 = MFMA32(a1, vf1, o0);
    o1 = MFMA32(a1, vf3, o1);
}

// ---------------------------------------------------------------------------
// Kernel 3: LDS-staged split-Q retention.
// Grid 512 = 16 pairs x 32 heads (h = bid&31 -> head-home XCD locality).
// Block: high tile ht=31-p (64 rows) + low tile p, merged s-sweep J=0..ht,
// 16KB K/V staged per period via global_load_lds, double-buffered.
// Waves: w0/w1 own high rows [0-31]/[32-63]; w2/w3 own low rows, and in
// phase B (J>p) pick up high's odd s-subtile (split-K partials, merged once).
// Uniform 33 compute-units per wave.
// ---------------------------------------------------------------------------
__global__ __launch_bounds__(256, 2)
void retention_mfma_kernel(const ushort* __restrict__ qfrag,
                           const ushort* __restrict__ kfrag,
                           const ushort* __restrict__ vfrag,
                           float* __restrict__ out) {
    __shared__ ushort buf[2][8192];            // 2 x 16KB double buffer
    __shared__ float lds_red[2][2][32][32];    // 16KB high-partials
    __shared__ float lds_den[2][32];

    const int bid = blockIdx.x;
    const int p   = bid >> 5;          // 0..15
    const int h   = bid & 31;
    const int ht  = 31 - p;            // high tile index (64-row units)
    const int tid = threadIdx.x;
    const int w   = tid >> 6;          // wave 0..3
    const int lane = tid & 63;
    const int hi  = lane >> 5;
    const int l31 = lane & 31;
    const int lofs = hi * 256 + l31 * 8;

    // Q fragments: primary (own rows), secondary (high rows, w>=2 only)
    short8 qrA[4], qrB[4];
    {
        const int prim_t32 = (w < 2) ? (ht * 2 + w) : (p * 2 + (w - 2));
        const ushort* qa = qfrag + ((size_t)h * 64 + prim_t32) * TILE_STRIDE;
#pragma unroll
        for (int ks = 0; ks < 4; ++ks) qrA[ks] = ld8(qa + ks * 512 + lofs);
        if (w >= 2) {
            const int sec_t32 = ht * 2 + (w - 2);
            const ushort* qb = qfrag + ((size_t)h * 64 + sec_t32) * TILE_STRIDE;
#pragma unroll
            for (int ks = 0; ks < 4; ++ks) qrB[ks] = ld8(qb + ks * 512 + lofs);
        }
    }

    f32x16 a0, a1, b0, b1;
#pragma unroll
    for (int i = 0; i < 16; ++i) { a0[i] = 0.f; a1[i] = 0.f; b0[i] = 0.f; b1[i] = 0.f; }
    f32x2 dA, dB;
    dA[0] = 0.f; dA[1] = 0.f; dB[0] = 0.f; dB[1] = 0.f;

    const char* kgb = (const char*)(kfrag + (size_t)h * 64 * TILE_STRIDE);
    const char* vgb = (const char*)(vfrag + (size_t)h * 64 * TILE_STRIDE);

    // prologue: stage period 0
    stage16k(buf[0], kgb, vgb, tid);
    __syncthreads();

    int cur = 0;
    for (int J = 0; J <= ht; ++J) {
        if (J < ht)
            stage16k(buf[cur ^ 1], kgb + (size_t)(J + 1) * 8192,
                     vgb + (size_t)(J + 1) * 8192, tid);

        const ushort* K0 = &buf[cur][0];
        const ushort* K1 = &buf[cur][2048];
        const ushort* V0 = &buf[cur][4096];
        const ushort* V1 = &buf[cur][6144];

        if (J < p) {
            // phase A interior: all waves, both subs, FULL, primary rows
            unit32<0>(K0, V0, lofs, hi, l31, qrA, a0, a1, dA);
            unit32<0>(K1, V1, lofs, hi, l31, qrA, a0, a1, dA);
        } else if (J == p) {
            // low-tile diagonal period (high still strictly below diag)
            if (w < 2) {
                unit32<0>(K0, V0, lofs, hi, l31, qrA, a0, a1, dA);
                unit32<0>(K1, V1, lofs, hi, l31, qrA, a0, a1, dA);
            } else if (w == 2) {
                unit32<1>(K0, V0, lofs, hi, l31, qrA, a0, a1, dA);
                // sub1 fully masked -> skip
            } else {
                unit32<0>(K0, V0, lofs, hi, l31, qrA, a0, a1, dA);
                unit32<1>(K1, V1, lofs, hi, l31, qrA, a0, a1, dA);
            }
        } else if (J < ht) {
            // phase B: high only; w0/w1 take sub0, w2/w3 take sub1 (partials)
            if (w < 2) unit32<0>(K0, V0, lofs, hi, l31, qrA, a0, a1, dA);
            else       unit32<0>(K1, V1, lofs, hi, l31, qrB, b0, b1, dB);
        } else {
            // J == ht: high diagonal period
            if (w == 0)      unit32<1>(K0, V0, lofs, hi, l31, qrA, a0, a1, dA);
            else if (w == 1) unit32<0>(K0, V0, lofs, hi, l31, qrA, a0, a1, dA);
            else if (w == 3) unit32<1>(K1, V1, lofs, hi, l31, qrB, b0, b1, dB);
            // w == 2: sub1 vs rows 0-31 fully masked -> idle
        }

        __syncthreads();
        cur ^= 1;
    }

    // ---- epilogue ----
    float denA = dA[0] + dA[1];
    denA += __shfl_xor(denA, 32);
    float denB = dB[0] + dB[1];
    denB += __shfl_xor(denB, 32);

    if (w >= 2) {
        const int ww = w - 2;
#pragma unroll
        for (int r = 0; r < 16; ++r) {
            const int row = (r & 3) + 8 * (r >> 2) + 4 * hi;
            lds_red[ww][0][row][l31] = b0[r];
            lds_red[ww][1][row][l31] = b1[r];
        }
        if (hi == 0) lds_den[ww][l31] = denB;
    }
    __syncthreads();

    if (w < 2) {
        // high rows: own acc + partner (w+2) partials
        const float dlane = denA + lds_den[w][l31];   // denom for t-col l31
#pragma unroll
        for (int r = 0; r < 16; ++r) {
            const int row = (r & 3) + 8 * (r >> 2) + 4 * hi;
            const float s0 = a0[r] + lds_red[w][0][row][l31];
            const float s1 = a1[r] + lds_red[w][1][row][l31];
            const float dt = __shfl(dlane, row);
            const float inv = 1.f / fmaxf(dt, 1.f);
            const int t = ht * 64 + w * 32 + row;
            float* op = out + ((size_t)t * H_DIM + h) * 64;
            op[l31]      = s0 * inv;
            op[32 + l31] = s1 * inv;
        }
    } else {
        // low rows: complete in accA
#pragma unroll
        for (int r = 0; r < 16; ++r) {
            const int row = (r & 3) + 8 * (r >> 2) + 4 * hi;
            const float dt = __shfl(denA, row);
            const float inv = 1.f / fmaxf(dt, 1.f);
            const int t = p * 64 + (w - 2) * 32 + row;
            float* op = out + ((size_t)t * H_DIM + h) * 64;
            op[l31]      = a0[r] * inv;
            op[32 + l31] = a1[r] * inv;
        }
    }
}

// ---------------------------------------------------------------------------
extern "C" void kernel_launch(void* const* d_in, const int* in_sizes, int n_in,
                              void* d_out, int out_size, void* d_ws, size_t ws_size,
                              hipStream_t stream) {
    const float* q = (const float*)d_in[0];
    const float* k = (const float*)d_in[1];
    const float* v = (const float*)d_in[2];
    const float* g = (const float*)d_in[3];
    float* out = (float*)d_out;

    const size_t GC_BYTES = (size_t)H_DIM * T_DIM * sizeof(float);   // 256 KB
    const size_t BF_ELEMS = (size_t)H_DIM * T_DIM * D_DIM;           // 4.2M ushorts

    float* gc = (float*)d_ws;
    ushort* qfrag = (ushort*)((char*)d_ws + GC_BYTES);
    ushort* kfrag = qfrag + BF_ELEMS;
    ushort* vfrag = kfrag + BF_ELEMS;

    cumsum_g_kernel<<<H_DIM, 256, 0, stream>>>(g, gc);
    prep_kernel<<<dim3(H_DIM, T_DIM / 64), 256, 0, stream>>>(q, k, v, gc,
                                                             qfrag, kfrag, vfrag);
    retention_mfma_kernel<<<16 * H_DIM, 256, 0, stream>>>(qfrag, kfrag, vfrag, out);
}

// Round 8
// 46.558 us; speedup vs baseline: 1.1722x; 1.1722x over previous
//
#include <hip/hip_runtime.h>

// Problem constants (reference: B=1, T=2048, H=32, D=64, SCALE=1/64, DEG=2)
#define T_DIM 2048
#define H_DIM 32
#define D_DIM 64
#define SCALE_F 0.015625f
#define TILE_STRIDE 2048    // ushorts per (h, 32-row frag tile) = 4KB

typedef unsigned short ushort;
typedef __attribute__((ext_vector_type(8))) short short8;   // 8 bf16
typedef __attribute__((ext_vector_type(16))) float f32x16;  // 32x32 MFMA acc
typedef __attribute__((ext_vector_type(2))) float f32x2;    // packed f32 math
typedef __attribute__((ext_vector_type(4))) float f32x4;

#define MFMA32(A, B, C) __builtin_amdgcn_mfma_f32_32x32x16_bf16((A), (B), (C), 0, 0, 0)

// ---------------------------------------------------------------------------
// Kernel 1: per-head inclusive cumsum of g over T -> gc stored [H][T]  (B=1)
// ---------------------------------------------------------------------------
__global__ __launch_bounds__(256)
void cumsum_g_kernel(const float* __restrict__ g, float* __restrict__ gc) {
    const int h = blockIdx.x;
    const int tid = threadIdx.x;
    const int PER = T_DIM / 256;        // 8

    __shared__ float sums[256];

    float loc[8];
    float run = 0.f;
    const int t0 = tid * PER;
    for (int i = 0; i < PER; ++i) {
        run += g[(size_t)(t0 + i) * H_DIM + h];
        loc[i] = run;
    }
    sums[tid] = run;
    __syncthreads();

    for (int off = 1; off < 256; off <<= 1) {
        float vv = (tid >= off) ? sums[tid - off] : 0.f;
        __syncthreads();
        sums[tid] += vv;
        __syncthreads();
    }
    float excl = (tid == 0) ? 0.f : sums[tid - 1];

    for (int i = 0; i < PER; ++i)
        gc[(size_t)h * T_DIM + t0 + i] = excl + loc[i];
}

// ---------------------------------------------------------------------------
__device__ __forceinline__ ushort f2bf(float x) {
    unsigned u = __float_as_uint(x);
    unsigned r = (u + 0x7fffu + ((u >> 16) & 1u)) >> 16;
    return (ushort)r;
}

// ---------------------------------------------------------------------------
// Prep: frag-major bf16 buffers so ALL main-loop frag loads coalesce.
//   qfrag/kfrag: [h][t32][ks(4)][hi(2)][l31(32)][8]  content q̂/k̂[32*t32+l31][16ks+8hi+j]
//   vfrag:       [h][s32][dblk(2)][kh2(2)][hi(2)][l31(32)][8]
//                 content v̂[32*s32+16kh2+8hi+j][32dblk+l31]
// q̂ = q*SCALE*exp(gc/2), k̂ = k*exp(-gc/2), v̂ = bf16(v).
// ---------------------------------------------------------------------------
__global__ __launch_bounds__(256)
void prep_kernel(const float* __restrict__ q, const float* __restrict__ k,
                 const float* __restrict__ v, const float* __restrict__ gc,
                 ushort* __restrict__ qfrag, ushort* __restrict__ kfrag,
                 ushort* __restrict__ vfrag) {
    __shared__ ushort qt_l[64 * 64];   // swizzled [row][slot] 16B chunks
    __shared__ ushort kt_l[64 * 64];

    const int h   = blockIdx.x;
    const int tt  = blockIdx.y;        // 64-row chunk
    const int tid = threadIdx.x;

    // ---- stage q̂,k̂ rows into swizzled LDS (coalesced f32 reads) ----
    {
        const int r    = tid >> 2;          // 0..63
        const int dseg = (tid & 3) * 16;    // 16 floats
        const int t    = tt * 64 + r;
        const float gct = gc[(size_t)h * T_DIM + t];
        const float eq = SCALE_F * __expf(0.5f * gct);
        const float ek = __expf(-0.5f * gct);
        const float* qp = q + ((size_t)t * H_DIM + h) * 64 + dseg;
        const float* kp = k + ((size_t)t * H_DIM + h) * 64 + dseg;
        union { ushort u[16]; uint4 uu[2]; } oq, ok;
#pragma unroll
        for (int i = 0; i < 16; ++i) {
            oq.u[i] = f2bf(qp[i] * eq);
            ok.u[i] = f2bf(kp[i] * ek);
        }
        const int c0 = (tid & 3) * 2;       // 16B chunk index base
#pragma unroll
        for (int cc = 0; cc < 2; ++cc) {
            const int slot = (c0 + cc) ^ (r & 7);
            *reinterpret_cast<uint4*>(&qt_l[r * 64 + slot * 8]) = oq.uu[cc];
            *reinterpret_cast<uint4*>(&kt_l[r * 64 + slot * 8]) = ok.uu[cc];
        }
    }
    __syncthreads();

    // ---- q/k frag writes: 512 16B-chunks each, coalesced stores ----
#pragma unroll
    for (int n = 0; n < 2; ++n) {
        const int ch   = tid + 256 * n;     // 0..511
        const int l31  = ch & 31;
        const int hi   = (ch >> 5) & 1;
        const int ks   = (ch >> 6) & 3;
        const int t32r = ch >> 8;           // 0/1
        const int row  = t32r * 32 + l31;
        const int slot = (2 * ks + hi) ^ (row & 7);
        uint4 qq = *reinterpret_cast<const uint4*>(&qt_l[row * 64 + slot * 8]);
        uint4 kk = *reinterpret_cast<const uint4*>(&kt_l[row * 64 + slot * 8]);
        const size_t base = ((size_t)h * 64 + tt * 2 + t32r) * TILE_STRIDE
                          + (size_t)(((ks * 2 + hi) * 32) + l31) * 8;
        *reinterpret_cast<uint4*>(qfrag + base) = qq;
        *reinterpret_cast<uint4*>(kfrag + base) = kk;
    }

    // ---- v frags: direct global gather (all loads/stores coalesced) ----
#pragma unroll
    for (int n = 0; n < 2; ++n) {
        const int c9   = (tid >> 5) + 8 * n;  // 0..15
        const int l31  = tid & 31;
        const int hi   = c9 & 1;
        const int kh2  = (c9 >> 1) & 1;
        const int dblk = (c9 >> 2) & 1;
        const int s32r = c9 >> 3;
        const int tb = tt * 64 + s32r * 32 + kh2 * 16 + hi * 8;
        union { ushort u[8]; uint4 uu; } ov;
#pragma unroll
        for (int j = 0; j < 8; ++j)
            ov.u[j] = f2bf(v[((size_t)(tb + j) * H_DIM + h) * 64 + dblk * 32 + l31]);
        const size_t base = ((size_t)h * 64 + tt * 2 + s32r) * TILE_STRIDE
                          + (size_t)((((dblk * 2 + kh2) * 2 + hi) * 32) + l31) * 8;
        *reinterpret_cast<uint4*>(vfrag + base) = ov.uu;
    }
}

// ---------------------------------------------------------------------------
// Main kernel helpers
// ---------------------------------------------------------------------------
__device__ __forceinline__ short8 ld8(const ushort* p) {
    return *reinterpret_cast<const short8*>(p);
}

__device__ __forceinline__ unsigned cvt_pk_bf16(float lo, float hi) {
    unsigned r;
    asm("v_cvt_pk_bf16_f32 %0, %1, %2" : "=v"(r) : "v"(lo), "v"(hi));
    return r;
}

// Pack 8 f32 W-values (4 f32x2 pairs, C-layout half) into the PV A-operand
// fragment via cvt_pk + permlane32_swap. (Layout verified R3-R7.)
__device__ __forceinline__ short8 pack_w2(const f32x2* w2) {
    unsigned p0 = cvt_pk_bf16(w2[0][0], w2[0][1]);
    unsigned p1 = cvt_pk_bf16(w2[1][0], w2[1][1]);
    unsigned p2 = cvt_pk_bf16(w2[2][0], w2[2][1]);
    unsigned p3 = cvt_pk_bf16(w2[3][0], w2[3][1]);
    asm("v_permlane32_swap_b32 %0, %1" : "+v"(p0), "+v"(p2));
    asm("v_permlane32_swap_b32 %0, %1" : "+v"(p1), "+v"(p3));
    union { unsigned u[4]; short8 s; } af;
    af.u[0] = p0; af.u[1] = p1; af.u[2] = p2; af.u[3] = p3;
    return af.s;
}

// Async 16B-per-lane global -> LDS copy (wave-uniform LDS base + lane*16).
__device__ __forceinline__ void gll16(const void* g, void* l) {
    __builtin_amdgcn_global_load_lds(
        (const __attribute__((address_space(1))) unsigned int*)g,
        (__attribute__((address_space(3))) unsigned int*)l, 16, 0, 0);
}

// Stage one 128-s period: K 16KB + V 16KB into a 32KB LDS buffer (linear).
// 512 threads x 4 x 16B.
__device__ __forceinline__ void stage32k(ushort* dst, const char* ksrc,
                                         const char* vsrc, int tid) {
    char* d = (char*)dst + (tid >> 6) * 1024;   // wave-uniform base
    const int lo = tid * 16;                    // lane-linear global offset
    gll16(ksrc + lo,        d);
    gll16(ksrc + 8192 + lo, d + 8192);
    gll16(vsrc + lo,        d + 16384);
    gll16(vsrc + 8192 + lo, d + 24576);
}

// One 32s x 32q unit from LDS. MODE 0: full, 1: diagonal (s_local <= l31).
template<int MODE>
__device__ __forceinline__ void unit32(
    const ushort* ldsK, const ushort* ldsV,
    int lofs, int hi, int l31,
    const short8 (&qr)[4], f32x16& o0, f32x16& o1, f32x2& den2)
{
    const short8 kf0 = ld8(ldsK + lofs);
    const short8 kf1 = ld8(ldsK + 512 + lofs);
    const short8 kf2 = ld8(ldsK + 1024 + lofs);
    const short8 kf3 = ld8(ldsK + 1536 + lofs);
    const short8 vf0 = ld8(ldsV + lofs);           // dblk0 kh2=0
    const short8 vf1 = ld8(ldsV + 512 + lofs);     // dblk0 kh2=1
    const short8 vf2 = ld8(ldsV + 1024 + lofs);    // dblk1 kh2=0
    const short8 vf3 = ld8(ldsV + 1536 + lofs);    // dblk1 kh2=1

    f32x16 c;
#pragma unroll
    for (int i = 0; i < 16; ++i) c[i] = 0.f;
    c = MFMA32(kf0, qr[0], c);
    c = MFMA32(kf1, qr[1], c);
    c = MFMA32(kf2, qr[2], c);
    c = MFMA32(kf3, qr[3], c);

    f32x2 w2[8];
#pragma unroll
    for (int i = 0; i < 8; ++i) {
        const int r0 = 2 * i;
        f32x2 x; x[0] = c[r0]; x[1] = c[r0 + 1];
        f32x2 ww = x * x;
        if (MODE == 1) {
            const int sl0 = (r0 & 3) + 8 * (r0 >> 2) + 4 * hi;
            ww[0] = (sl0 <= l31) ? ww[0] : 0.f;
            ww[1] = (sl0 + 1 <= l31) ? ww[1] : 0.f;
        }
        w2[i] = ww;
        den2 += ww;
    }
    const short8 a0 = pack_w2(&w2[0]);     // kh2 = 0
    o0 = MFMA32(a0, vf0, o0);
    o1 = MFMA32(a0, vf2, o1);
    const short8 a1 = pack_w2(&w2[4]);     // kh2 = 1
    o0 = MFMA32(a1, vf1, o0);
    o1 = MFMA32(a1, vf3, o1);
}

// ---------------------------------------------------------------------------
// Kernel 3: 8-wave, 128-row q-block retention (m214-attn-shaped).
// Grid 512: h=(bid&7)+8*((bid>>3)&3) (head-home XCD), qb from balance map
// (blocks r and r+8 sum to 15 -> co-resident blocks balanced).
// Waves: (qi = w&3 -> q-sub 4qb+qi, si = w>>2 -> s-slot). Period = 128 s-rows
// staged 32KB via global_load_lds, ping-pong, ONE barrier per period.
// Per wave per period: units (4J+si) and (4J+2+si) vs its q-sub.
// ---------------------------------------------------------------------------
__global__ __launch_bounds__(512, 4)
void retention_mfma_kernel(const ushort* __restrict__ qfrag,
                           const ushort* __restrict__ kfrag,
                           const ushort* __restrict__ vfrag,
                           float* __restrict__ out) {
    __shared__ ushort buf[2][16384];   // 2 x 32KB staging (64KB total)

    const int bid = blockIdx.x;
    const int h   = (bid & 7) + 8 * ((bid >> 3) & 3);
    const int r   = bid >> 5;                       // 0..15
    const int qb  = (r < 8) ? (2 * r) : (31 - 2 * r + 16 - 16); // see below
    // balance map: r<8 -> 2r (0,2,..,14); r>=8 -> 31-2r -> (15,13,..,1)
    const int qbb = (r < 8) ? (2 * r) : (31 - 2 * (r - 8) - 16 + 16);
    (void)qb; (void)qbb;
    const int QB  = (r < 8) ? (2 * r) : (15 - 2 * (r - 8));

    const int tid = threadIdx.x;
    const int w   = tid >> 6;          // wave 0..7
    const int qi  = w & 3;             // q-sub within block
    const int si  = w >> 2;            // s-slot 0/1
    const int lane = tid & 63;
    const int hi  = lane >> 5;
    const int l31 = lane & 31;
    const int lofs = hi * 256 + l31 * 8;
    const int myT32 = 4 * QB + qi;     // my q-sub's global 32-row index

    // Q frags (16 VGPR)
    short8 qr[4];
    {
        const ushort* qp = qfrag + ((size_t)h * 64 + myT32) * TILE_STRIDE;
#pragma unroll
        for (int ks = 0; ks < 4; ++ks) qr[ks] = ld8(qp + ks * 512 + lofs);
    }

    f32x16 o0, o1;
#pragma unroll
    for (int i = 0; i < 16; ++i) { o0[i] = 0.f; o1[i] = 0.f; }
    f32x2 d2; d2[0] = 0.f; d2[1] = 0.f;

    const char* kgb = (const char*)(kfrag + (size_t)h * 64 * TILE_STRIDE);
    const char* vgb = (const char*)(vfrag + (size_t)h * 64 * TILE_STRIDE);

    // prologue: stage period 0
    stage32k(buf[0], kgb, vgb, tid);
    __syncthreads();

    for (int J = 0; J <= QB; ++J) {
        if (J < QB)
            stage32k(buf[(J + 1) & 1], kgb + (size_t)(J + 1) * 16384,
                     vgb + (size_t)(J + 1) * 16384, tid);

        const ushort* bK = buf[J & 1];
        const ushort* bV = bK + 8192;
        const int c1 = 4 * J + si;
        const int c2 = c1 + 2;

        if (c1 < myT32)
            unit32<0>(bK + si * 2048, bV + si * 2048, lofs, hi, l31, qr, o0, o1, d2);
        else if (c1 == myT32)
            unit32<1>(bK + si * 2048, bV + si * 2048, lofs, hi, l31, qr, o0, o1, d2);

        if (c2 < myT32)
            unit32<0>(bK + (2 + si) * 2048, bV + (2 + si) * 2048, lofs, hi, l31, qr, o0, o1, d2);
        else if (c2 == myT32)
            unit32<1>(bK + (2 + si) * 2048, bV + (2 + si) * 2048, lofs, hi, l31, qr, o0, o1, d2);

        __syncthreads();   // J+1 staged AND all reads of buf[J&1] done
    }

    // ---- epilogue: merge si-partials in (now free) staging LDS ----
    float* pm  = (float*)(&buf[0][0]);   // 32KB: [qi][row32][col64]
    float* pmd = (float*)(&buf[1][0]);   // den: [qi*2+si][32]

    float den = d2[0] + d2[1];
    den += __shfl_xor(den, 32);
    if (hi == 0) pmd[(qi * 2 + si) * 32 + l31] = den;

    if (si == 0) {
#pragma unroll
        for (int rr = 0; rr < 16; ++rr) {
            const int row = (rr & 3) + 8 * (rr >> 2) + 4 * hi;
            pm[(qi * 32 + row) * 64 + l31]      = o0[rr];
            pm[(qi * 32 + row) * 64 + 32 + l31] = o1[rr];
        }
    }
    __syncthreads();
    if (si == 1) {
#pragma unroll
        for (int rr = 0; rr < 16; ++rr) {
            const int row = (rr & 3) + 8 * (rr >> 2) + 4 * hi;
            pm[(qi * 32 + row) * 64 + l31]      += o0[rr];
            pm[(qi * 32 + row) * 64 + 32 + l31] += o1[rr];
        }
    }
    __syncthreads();

    // final write: 512 threads -> 128 rows x 64 cols
    {
        const int row  = tid >> 2;          // 0..127
        const int qq   = row >> 5;
        const int r32  = row & 31;
        const int dseg = (tid & 3) * 16;
        const float dtot = pmd[(qq * 2 + 0) * 32 + r32] + pmd[(qq * 2 + 1) * 32 + r32];
        const float inv = 1.f / fmaxf(dtot, 1.f);
        const float* src = pm + (qq * 32 + r32) * 64 + dseg;
        float* dst = out + ((size_t)(QB * 128 + row) * H_DIM + h) * 64 + dseg;
#pragma unroll
        for (int jv = 0; jv < 4; ++jv) {
            f32x4 s = *reinterpret_cast<const f32x4*>(src + 4 * jv);
            s *= inv;
            *reinterpret_cast<f32x4*>(dst + 4 * jv) = s;
        }
    }
}

// ---------------------------------------------------------------------------
extern "C" void kernel_launch(void* const* d_in, const int* in_sizes, int n_in,
                              void* d_out, int out_size, void* d_ws, size_t ws_size,
                              hipStream_t stream) {
    const float* q = (const float*)d_in[0];
    const float* k = (const float*)d_in[1];
    const float* v = (const float*)d_in[2];
    const float* g = (const float*)d_in[3];
    float* out = (float*)d_out;

    const size_t GC_BYTES = (size_t)H_DIM * T_DIM * sizeof(float);   // 256 KB
    const size_t BF_ELEMS = (size_t)H_DIM * T_DIM * D_DIM;           // 4.2M ushorts

    float* gc = (float*)d_ws;
    ushort* qfrag = (ushort*)((char*)d_ws + GC_BYTES);
    ushort* kfrag = qfrag + BF_ELEMS;
    ushort* vfrag = kfrag + BF_ELEMS;

    cumsum_g_kernel<<<H_DIM, 256, 0, stream>>>(g, gc);
    prep_kernel<<<dim3(H_DIM, T_DIM / 64), 256, 0, stream>>>(q, k, v, gc,
                                                             qfrag, kfrag, vfrag);
    retention_mfma_kernel<<<512, 512, 0, stream>>>(qfrag, kfrag, vfrag, out);
}